// Round 4
// baseline (484.721 us; speedup 1.0000x reference)
//
#include <hip/hip_runtime.h>
#include <hip/hip_bf16.h>

#define DEV static __device__ __forceinline__

typedef short bf16x8_t __attribute__((ext_vector_type(8)));
typedef float f32x4 __attribute__((ext_vector_type(4)));

DEV int reflect_idx(int q, int L) {
    q = q < 0 ? -q : q;
    q = q >= L ? 2 * L - 2 - q : q;
    return q;
}

DEV unsigned short f2bf(float f) {
    unsigned int b = __float_as_uint(f);
    unsigned int r = (b + 0x7FFFu + ((b >> 16) & 1u)) >> 16;
    return (unsigned short)r;
}
DEV float bf2f(unsigned short u) {
    return __uint_as_float(((unsigned int)u) << 16);
}

// ---------------------------------------------------------------------------
__global__ void k0_init(float* lacc) {
    if (threadIdx.x < 8) lacc[threadIdx.x] = 0.0f;
}

// prep: w1 [256co][512ci][3kk] fp32 -> wb [3kk][256co][512ci] bf16
__global__ void kw1b(const float* __restrict__ w1, unsigned short* __restrict__ wb) {
    int idx = blockIdx.x * 256 + threadIdx.x;   // 393216
    int kk = idx >> 17;
    int rem = idx & 131071;
    int co = rem >> 9;
    int ci = rem & 511;
    wb[idx] = f2bf(w1[(co * 512 + ci) * 3 + kk]);
}

// prep: w2 [32co][256ci][3kk] fp32 -> w2b [3kk][32co][256ci] bf16
__global__ void kw2b(const float* __restrict__ w2, unsigned short* __restrict__ w2b) {
    int idx = blockIdx.x * 256 + threadIdx.x;   // 24576 = kk*8192 + co*256 + ci
    int ci = idx & 255;
    int co = (idx >> 8) & 31;
    int kk = idx >> 13;
    w2b[idx] = f2bf(w2[(co * 256 + ci) * 3 + kk]);
}

// prep: transpose x[n][512ci][1024t] fp32 -> xb[nr][1024t][512ci] bf16
__global__ __launch_bounds__(256) void kx_t(const float* __restrict__ x,
                                            unsigned short* __restrict__ xb, int n0) {
    __shared__ float ls[64][65];
    const int tid = threadIdx.x;
    const int t0 = blockIdx.x * 64, ci0 = blockIdx.y * 64;
    const int n = n0 + blockIdx.z;
    const float* xp = x + ((size_t)n * 512 + ci0) * 1024 + t0;
    for (int idx = tid; idx < 1024; idx += 256) {
        int r = idx >> 4, c4 = (idx & 15) * 4;
        float4 v = *(const float4*)(xp + r * 1024 + c4);
        ls[r][c4] = v.x; ls[r][c4 + 1] = v.y; ls[r][c4 + 2] = v.z; ls[r][c4 + 3] = v.w;
    }
    __syncthreads();
    unsigned short* xo = xb + ((size_t)blockIdx.z * 1024 + t0) * 512 + ci0;
#pragma unroll
    for (int p = 0; p < 2; ++p) {
        int trow = (tid >> 3) + p * 32;
        int cj = (tid & 7) * 8;
        unsigned short pk[8];
#pragma unroll
        for (int j = 0; j < 8; ++j) pk[j] = f2bf(ls[cj + j][trow]);
        *(uint4*)(xo + (size_t)trow * 512 + cj) = *(const uint4*)pk;
    }
}

// ---------------------------------------------------------------------------
// K1 v2: conv1 (512->256, d=8, reflect) + bn1 + relu via bf16 MFMA 16x16x32.
// BARRIER-FREE K-loop: A-fragments loaded directly from xb[t][ci] as per-lane
// contiguous 16B global loads (9 fragment rows, register double-buffered);
// W single-buffered from L2, consumed in load order. No LDS until epilogue.
// Output TRANSPOSED: y1t[n][1024t][256co] bf16.
__global__ __launch_bounds__(256, 2) void k1_mfma(
    const unsigned short* __restrict__ xb, const unsigned short* __restrict__ wb,
    const float* __restrict__ g, const float* __restrict__ be,
    const float* __restrict__ mn, const float* __restrict__ vr,
    unsigned short* __restrict__ y1t, int n0)
{
    const int tid  = threadIdx.x;
    const int lane = tid & 63;
    const int w    = tid >> 6;
    const int tq   = lane & 15;
    const int qd   = lane >> 4;
    const int t0   = blockIdx.x * 64;
    const int nr   = blockIdx.y;
    const int n    = n0 + nr;

    __shared__ unsigned short us1[64 * 264];   // epilogue transpose only (33.8 KB)

    // 9 per-lane X row pointers: rows t0-8+8s+tq (s=0..8), k-offset qd*8
    const unsigned short* xp[9];
#pragma unroll
    for (int s = 0; s < 9; ++s) {
        int row = reflect_idx(t0 - 8 + s * 8 + tq, 1024);
        xp[s] = xb + ((size_t)nr * 1024 + row) * 512 + qd * 8;
    }
    const unsigned short* wlane = wb + (size_t)(w * 64 + tq) * 512 + qd * 8;

    f32x4 acc[4][4];
#pragma unroll
    for (int a = 0; a < 4; ++a)
#pragma unroll
        for (int b = 0; b < 4; ++b) acc[a][b] = (f32x4){0.f, 0.f, 0.f, 0.f};

    // prologue: X fragments for chunk 0
    bf16x8_t Xf[9];
#pragma unroll
    for (int s = 0; s < 9; ++s) Xf[s] = *(const bf16x8_t*)xp[s];

#pragma unroll
    for (int c = 0; c < 16; ++c) {
        // W for this chunk (L2-hot, single-buffered, consumed in load order)
        bf16x8_t Wf[12];
#pragma unroll
        for (int cs = 0; cs < 4; ++cs)
#pragma unroll
            for (int kk = 0; kk < 3; ++kk)
                Wf[cs * 3 + kk] = *(const bf16x8_t*)(wlane +
                    (size_t)(kk * 256 + cs * 16) * 512 + c * 32);
        // X for next chunk (register double-buffer)
        bf16x8_t Xn[9];
        if (c < 15) {
#pragma unroll
            for (int s = 0; s < 9; ++s)
                Xn[s] = *(const bf16x8_t*)(xp[s] + (c + 1) * 32);
        }
        // 48 MFMAs: consume Wf in load order (cs outer), 4 independent acc
        // chains (ts) between each kk-dependence link
#pragma unroll
        for (int cs = 0; cs < 4; ++cs)
#pragma unroll
            for (int kk = 0; kk < 3; ++kk)
#pragma unroll
                for (int ts = 0; ts < 4; ++ts)
                    acc[ts][cs] = __builtin_amdgcn_mfma_f32_16x16x32_bf16(
                        Xf[2 * ts + kk], Wf[cs * 3 + kk], acc[ts][cs], 0, 0, 0);
        if (c < 15) {
#pragma unroll
            for (int s = 0; s < 9; ++s) Xf[s] = Xn[s];
        }
    }

    // epilogue: bn + relu -> bf16 -> LDS transpose [t][co] -> coalesced store
#pragma unroll
    for (int cs = 0; cs < 4; ++cs) {
        int co = w * 64 + cs * 16 + tq;
        float iv = g[co] / sqrtf(vr[co] + 1e-5f);
        float sh = be[co] - mn[co] * iv;
#pragma unroll
        for (int ts = 0; ts < 4; ++ts)
#pragma unroll
            for (int rg = 0; rg < 4; ++rg)
                us1[(ts * 16 + qd * 4 + rg) * 264 + co] =
                    f2bf(fmaxf(fmaf(acc[ts][cs][rg], iv, sh), 0.0f));
    }
    __syncthreads();
    const int row = tid >> 2, q = tid & 3;
    unsigned short* yp = y1t + ((size_t)n * 1024 + t0 + row) * 256 + q * 64;
#pragma unroll
    for (int j = 0; j < 8; ++j)
        *(uint4*)(yp + j * 8) = *(const uint4*)&us1[row * 264 + q * 64 + j * 8];
}

// ---------------------------------------------------------------------------
// K2: upsample2(y1t) -> conv2 (256->32, d=16) + bn2 + relu via bf16 MFMA.
// Output TRANSPOSED fp32: y2t[n][2048t][32co].  (unchanged)
__global__ __launch_bounds__(256, 2) void k2_mfma(
    const unsigned short* __restrict__ y1t, const unsigned short* __restrict__ w2b,
    const float* __restrict__ g, const float* __restrict__ be,
    const float* __restrict__ mn, const float* __restrict__ vr,
    float* __restrict__ y2t)
{
    const int tid  = threadIdx.x;
    const int lane = tid & 63;
    const int w    = tid >> 6;
    const int tq   = lane & 15;
    const int qd   = lane >> 4;
    const int t0   = blockIdx.x * 256;
    const int n    = blockIdx.y;

    __shared__ union SM {
        unsigned short us[288 * 40];
        float tr[256 * 36];
    } sm;

    f32x4 acc[4][2];
#pragma unroll
    for (int a = 0; a < 4; ++a)
#pragma unroll
        for (int b = 0; b < 2; ++b) acc[a][b] = (f32x4){0.f, 0.f, 0.f, 0.f};

    const unsigned short* yn = y1t + (size_t)n * 1024 * 256;

    for (int ch = 0; ch < 8; ++ch) {
        const int ci0 = ch * 32;
        __syncthreads();
        for (int idx = tid; idx < 1152; idx += 256) {
            int r = idx >> 2, gq = idx & 3;
            int u = reflect_idx(t0 - 16 + r, 2048);
            float src = fmaxf((float)u * 0.5f - 0.25f, 0.0f);
            int i0 = (int)src;
            float wl = src - (float)i0;
            int i1 = i0 + 1 > 1023 ? 1023 : i0 + 1;
            const unsigned short* p0 = yn + (size_t)i0 * 256 + ci0 + gq * 8;
            const unsigned short* p1 = yn + (size_t)i1 * 256 + ci0 + gq * 8;
            uint4 ua = *(const uint4*)p0;
            uint4 ub = *(const uint4*)p1;
            const unsigned short* sa = (const unsigned short*)&ua;
            const unsigned short* sb = (const unsigned short*)&ub;
            unsigned short pk[8];
#pragma unroll
            for (int j = 0; j < 8; ++j) {
                float a = bf2f(sa[j]);
                float b = bf2f(sb[j]);
                pk[j] = f2bf(a + wl * (b - a));
            }
            *(uint4*)&sm.us[r * 40 + gq * 8] = *(const uint4*)pk;
        }
        __syncthreads();

        bf16x8_t Bf[2][3];
#pragma unroll
        for (int cs = 0; cs < 2; ++cs)
#pragma unroll
            for (int kk = 0; kk < 3; ++kk)
                Bf[cs][kk] = *(const bf16x8_t*)(w2b +
                    ((size_t)(kk * 32 + cs * 16 + tq)) * 256 + ci0 + qd * 8);

        bf16x8_t Af[6];
#pragma unroll
        for (int s = 0; s < 6; ++s)
            Af[s] = *(const bf16x8_t*)&sm.us[(w * 64 + s * 16 + tq) * 40 + qd * 8];

#pragma unroll
        for (int ts = 0; ts < 4; ++ts)
#pragma unroll
            for (int cs = 0; cs < 2; ++cs)
#pragma unroll
                for (int kk = 0; kk < 3; ++kk)
                    acc[ts][cs] = __builtin_amdgcn_mfma_f32_16x16x32_bf16(
                        Af[ts + kk], Bf[cs][kk], acc[ts][cs], 0, 0, 0);
    }

    __syncthreads();
#pragma unroll
    for (int cs = 0; cs < 2; ++cs) {
        int co = cs * 16 + tq;
        float iv = g[co] / sqrtf(vr[co] + 1e-5f);
        float sh = be[co] - mn[co] * iv;
#pragma unroll
        for (int ts = 0; ts < 4; ++ts)
#pragma unroll
            for (int rg = 0; rg < 4; ++rg) {
                int tl = w * 64 + ts * 16 + qd * 4 + rg;
                sm.tr[tl * 36 + co] = fmaxf(fmaf(acc[ts][cs][rg], iv, sh), 0.0f);
            }
    }
    __syncthreads();
    float* yo = y2t + ((size_t)n * 2048 + t0 + tid) * 32;
#pragma unroll
    for (int j = 0; j < 8; ++j)
        *(float4*)(yo + j * 4) = *(const float4*)&sm.tr[tid * 36 + j * 4];
}

// ---------------------------------------------------------------------------
// K3: upsample2(y2t) -> conv3 (32->3, d=32) + bias, transposed store (unchanged)
__global__ __launch_bounds__(256, 2) void k3_out(
    const float* __restrict__ y2t, const float* __restrict__ w3,
    const float* __restrict__ bias, float* __restrict__ out)
{
    const int tid = threadIdx.x;
    const int t0 = blockIdx.x * 256;
    const int n  = blockIdx.y;

    __shared__ float us[32 * 321];
    __shared__ float wsh[288];

    for (int idx = tid; idx < 288; idx += 256) wsh[idx] = w3[idx];

    const float* yn = y2t + (size_t)n * 2048 * 32;
    for (int idx = tid; idx < 1280; idx += 256) {
        int r = idx >> 2, gq = idx & 3;
        int u = reflect_idx(t0 - 32 + r, 4096);
        float src = fmaxf((float)u * 0.5f - 0.25f, 0.0f);
        int i0 = (int)src;
        float wl = src - (float)i0;
        int i1 = i0 + 1 > 2047 ? 2047 : i0 + 1;
        const float* p0 = yn + (size_t)i0 * 32 + gq * 8;
        const float* p1 = yn + (size_t)i1 * 32 + gq * 8;
        float4 a0 = *(const float4*)p0;
        float4 a1 = *(const float4*)(p0 + 4);
        float4 b0 = *(const float4*)p1;
        float4 b1 = *(const float4*)(p1 + 4);
        float v[8];
        v[0] = a0.x + wl * (b0.x - a0.x); v[1] = a0.y + wl * (b0.y - a0.y);
        v[2] = a0.z + wl * (b0.z - a0.z); v[3] = a0.w + wl * (b0.w - a0.w);
        v[4] = a1.x + wl * (b1.x - a1.x); v[5] = a1.y + wl * (b1.y - a1.y);
        v[6] = a1.z + wl * (b1.z - a1.z); v[7] = a1.w + wl * (b1.w - a1.w);
#pragma unroll
        for (int j = 0; j < 8; ++j)
            us[(gq * 8 + j) * 321 + r] = v[j];
    }
    __syncthreads();

    float a0 = 0.0f, a1 = 0.0f, a2 = 0.0f;
#pragma unroll 8
    for (int ci = 0; ci < 32; ++ci) {
        float x0 = us[ci * 321 + tid];
        float x1 = us[ci * 321 + tid + 32];
        float x2 = us[ci * 321 + tid + 64];
        a0 = fmaf(wsh[(0 * 32 + ci) * 3 + 0], x0, a0);
        a0 = fmaf(wsh[(0 * 32 + ci) * 3 + 1], x1, a0);
        a0 = fmaf(wsh[(0 * 32 + ci) * 3 + 2], x2, a0);
        a1 = fmaf(wsh[(1 * 32 + ci) * 3 + 0], x0, a1);
        a1 = fmaf(wsh[(1 * 32 + ci) * 3 + 1], x1, a1);
        a1 = fmaf(wsh[(1 * 32 + ci) * 3 + 2], x2, a1);
        a2 = fmaf(wsh[(2 * 32 + ci) * 3 + 0], x0, a2);
        a2 = fmaf(wsh[(2 * 32 + ci) * 3 + 1], x1, a2);
        a2 = fmaf(wsh[(2 * 32 + ci) * 3 + 2], x2, a2);
    }
    int b = n >> 2, s = n & 3;
    int t = t0 + tid;
    size_t ob = ((size_t)(b * 3) * 4096 + t) * 4 + s;
    out[ob]         = a0 + bias[0];
    out[ob + 16384] = a1 + bias[1];
    out[ob + 32768] = a2 + bias[2];
}

// ---------------------------------------------------------------------------
__global__ void k4a_valid(const float* __restrict__ tg, float* lacc) {
    __shared__ int flag;
    if (threadIdx.x == 0) flag = 0;
    __syncthreads();
    int b = blockIdx.x >> 2, s = blockIdx.x & 3;
    bool any = false;
    for (int idx = threadIdx.x; idx < 3 * 4096; idx += 256) {
        int c = idx >> 12, t = idx & 4095;
        float v = tg[((size_t)(b * 3 + c) * 4096 + t) * 4 + s];
        any |= (v != 0.0f);
    }
    if (any) flag = 1;
    __syncthreads();
    if (threadIdx.x == 0 && flag) atomicAdd((int*)(lacc + 1), 1);
}

__global__ __launch_bounds__(256) void k4b_ce(
    const float* __restrict__ x, const float* __restrict__ tg, float* lacc)
{
    int i = blockIdx.x * 256 + threadIdx.x;
    int s = i & 3;
    int t = (i >> 2) & 4095;
    int b = i >> 14;
    size_t base = ((size_t)(b * 3) * 4096 + t) * 4 + s;
    float x0 = x[base], x1 = x[base + 16384], x2 = x[base + 32768];
    float mx = fmaxf(x0, fmaxf(x1, x2));
    float e0 = expf(x0 - mx), e1 = expf(x1 - mx), e2 = expf(x2 - mx);
    float lse = mx + logf(e0 + e1 + e2);
    float g0 = tg[base], g1 = tg[base + 16384], g2 = tg[base + 32768];
    float v = g0 * (lse - x0) + g1 * (lse - x1) + g2 * (lse - x2);

    for (int off = 32; off > 0; off >>= 1) v += __shfl_down(v, off);
    __shared__ float wsum[4];
    int lane = threadIdx.x & 63, wid = threadIdx.x >> 6;
    if (lane == 0) wsum[wid] = v;
    __syncthreads();
    if (threadIdx.x == 0) {
        atomicAdd(lacc, wsum[0] + wsum[1] + wsum[2] + wsum[3]);
    }
}

__global__ void k4c_final(const float* lacc, float* out) {
    if (threadIdx.x == 0) {
        float sum = lacc[0];
        int num = ((const int*)lacc)[1];
        out[786432] = sum / ((float)num * 4096.0f);
    }
}

// ---------------------------------------------------------------------------
extern "C" void kernel_launch(void* const* d_in, const int* in_sizes, int n_in,
                              void* d_out, int out_size, void* d_ws, size_t ws_size,
                              hipStream_t stream) {
    (void)in_sizes; (void)n_in; (void)out_size;
    const float* fusion  = (const float*)d_in[0];
    const float* targets = (const float*)d_in[1];
    const float* w1  = (const float*)d_in[2];
    const float* g1  = (const float*)d_in[3];
    const float* be1 = (const float*)d_in[4];
    const float* mn1 = (const float*)d_in[5];
    const float* vr1 = (const float*)d_in[6];
    const float* w2  = (const float*)d_in[7];
    const float* g2  = (const float*)d_in[8];
    const float* be2 = (const float*)d_in[9];
    const float* mn2 = (const float*)d_in[10];
    const float* vr2 = (const float*)d_in[11];
    const float* w3  = (const float*)d_in[12];
    const float* b3  = (const float*)d_in[13];
    float* out = (float*)d_out;

    char* ws = (char*)d_ws;
    unsigned short* y1t = (unsigned short*)ws;              // 33,554,432 B
    unsigned short* xb  = (unsigned short*)(ws + 33554432); // 16 or 64 MB
    float* y2t = (float*)(ws + 33554432);                   // 16 MB, aliases xb

    const bool single = ws_size >= 101500000ull;
    size_t woff = single ? (33554432ull + 67108864ull) : (33554432ull + 16777216ull);
    unsigned short* wb  = (unsigned short*)(ws + woff);            // 786,432 B
    unsigned short* w2b = (unsigned short*)(ws + woff + 786432);   //  49,152 B
    float* lacc = (float*)(ws + woff + 786432 + 49152);            //     256 B

    k0_init<<<1, 64, 0, stream>>>(lacc);
    kw1b<<<1536, 256, 0, stream>>>(w1, wb);
    kw2b<<<96, 256, 0, stream>>>(w2, w2b);
    if (single) {
        kx_t<<<dim3(16, 8, 64), 256, 0, stream>>>(fusion, xb, 0);
        k1_mfma<<<dim3(16, 64), 256, 0, stream>>>(xb, wb, g1, be1, mn1, vr1, y1t, 0);
    } else {
        for (int r = 0; r < 4; ++r) {
            kx_t<<<dim3(16, 8, 16), 256, 0, stream>>>(fusion, xb, r * 16);
            k1_mfma<<<dim3(16, 16), 256, 0, stream>>>(xb, wb, g1, be1, mn1, vr1, y1t, r * 16);
        }
    }
    k2_mfma<<<dim3(8, 64), 256, 0, stream>>>(y1t, w2b, g2, be2, mn2, vr2, y2t);
    k3_out<<<dim3(16, 64), 256, 0, stream>>>(y2t, w3, b3, out);
    k4a_valid<<<64, 256, 0, stream>>>(targets, lacc);
    k4b_ce<<<1024, 256, 0, stream>>>(out, targets, lacc);
    k4c_final<<<1, 64, 0, stream>>>(lacc, out);
}

// Round 5
// 413.296 us; speedup vs baseline: 1.1728x; 1.1728x over previous
//
#include <hip/hip_runtime.h>
#include <hip/hip_bf16.h>

#define DEV static __device__ __forceinline__

typedef short bf16x8_t __attribute__((ext_vector_type(8)));
typedef float f32x4 __attribute__((ext_vector_type(4)));

#define GLDS16(gp, lp) __builtin_amdgcn_global_load_lds( \
    (const __attribute__((address_space(1))) void*)(gp), \
    (__attribute__((address_space(3))) void*)(lp), 16, 0, 0)

DEV int reflect_idx(int q, int L) {
    q = q < 0 ? -q : q;
    q = q >= L ? 2 * L - 2 - q : q;
    return q;
}

DEV unsigned short f2bf(float f) {
    unsigned int b = __float_as_uint(f);
    unsigned int r = (b + 0x7FFFu + ((b >> 16) & 1u)) >> 16;
    return (unsigned short)r;
}
DEV float bf2f(unsigned short u) {
    return __uint_as_float(((unsigned int)u) << 16);
}

// ---------------------------------------------------------------------------
__global__ void k0_init(float* lacc) {
    if (threadIdx.x < 8) lacc[threadIdx.x] = 0.0f;
}

// prep: w1 [256co][512ci][3kk] fp32 -> wb [3kk][256co][512ci] bf16
__global__ void kw1b(const float* __restrict__ w1, unsigned short* __restrict__ wb) {
    int idx = blockIdx.x * 256 + threadIdx.x;   // 393216
    int kk = idx >> 17;
    int rem = idx & 131071;
    int co = rem >> 9;
    int ci = rem & 511;
    wb[idx] = f2bf(w1[(co * 512 + ci) * 3 + kk]);
}

// prep: w2 [32co][256ci][3kk] fp32 -> w2b [3kk][32co][256ci] bf16
__global__ void kw2b(const float* __restrict__ w2, unsigned short* __restrict__ w2b) {
    int idx = blockIdx.x * 256 + threadIdx.x;   // 24576 = kk*8192 + co*256 + ci
    int ci = idx & 255;
    int co = (idx >> 8) & 31;
    int kk = idx >> 13;
    w2b[idx] = f2bf(w2[(co * 256 + ci) * 3 + kk]);
}

// prep: transpose x[n][512ci][1024t] fp32 -> xb[nr][1024t][512ci] bf16
__global__ __launch_bounds__(256) void kx_t(const float* __restrict__ x,
                                            unsigned short* __restrict__ xb, int n0) {
    __shared__ float ls[64][65];
    const int tid = threadIdx.x;
    const int t0 = blockIdx.x * 64, ci0 = blockIdx.y * 64;
    const int n = n0 + blockIdx.z;
    const float* xp = x + ((size_t)n * 512 + ci0) * 1024 + t0;
    for (int idx = tid; idx < 1024; idx += 256) {
        int r = idx >> 4, c4 = (idx & 15) * 4;
        float4 v = *(const float4*)(xp + r * 1024 + c4);
        ls[r][c4] = v.x; ls[r][c4 + 1] = v.y; ls[r][c4 + 2] = v.z; ls[r][c4 + 3] = v.w;
    }
    __syncthreads();
    unsigned short* xo = xb + ((size_t)blockIdx.z * 1024 + t0) * 512 + ci0;
#pragma unroll
    for (int p = 0; p < 2; ++p) {
        int trow = (tid >> 3) + p * 32;
        int cj = (tid & 7) * 8;
        unsigned short pk[8];
#pragma unroll
        for (int j = 0; j < 8; ++j) pk[j] = f2bf(ls[cj + j][trow]);
        *(uint4*)(xo + (size_t)trow * 512 + cj) = *(const uint4*)pk;
    }
}

// ---------------------------------------------------------------------------
// K1 v3: conv1 via bf16 MFMA 16x16x32; glds LDS staging (R3 core) with:
//  - BK=64 (two 32-ci planes per barrier interval, 96 MFMA/wave/interval)
//  - LDS cut to 20.5 KB (epilogue transpose 4-pass, union'd with staging)
//  - W loads issued before glds(c+1) so W-use waits vmcnt(3), prefetch flies
// Layout per buffer b: plane s (sub-chunk of 32 ci): rows 80 x 64B, swizzled
// (q' = q ^ ((row>>1)&3)) on the gather side. Output y1t[n][1024t][256co].
__global__ __launch_bounds__(256, 2) void k1_mfma(
    const unsigned short* __restrict__ xb, const unsigned short* __restrict__ wb,
    const float* __restrict__ g, const float* __restrict__ be,
    const float* __restrict__ mn, const float* __restrict__ vr,
    unsigned short* __restrict__ y1t, int n0)
{
    const int tid  = threadIdx.x;
    const int lane = tid & 63;
    const int w    = tid >> 6;
    const int tq   = lane & 15;
    const int qd   = lane >> 4;
    const int t0   = blockIdx.x * 64;
    const int nr   = blockIdx.y;
    const int n    = n0 + nr;

    __shared__ unsigned short smem[10240];   // 20480 B: 2 bufs x 2 planes x 80 rows x 32 ci

    // three glds lane-load slots per thread: l = i*256 + tid (l < 640)
    const unsigned short* gsrc[3];
#pragma unroll
    for (int i = 0; i < 3; ++i) {
        int l = i * 256 + tid;
        int sub = l >= 320 ? 1 : 0;
        int rr = l - sub * 320;
        int row = rr >> 2, q = rr & 3;
        int qp = q ^ ((row >> 1) & 3);
        gsrc[i] = xb + ((size_t)nr * 1024 + reflect_idx(t0 - 8 + row, 1024)) * 512
                     + sub * 32 + qp * 8;
    }
    const unsigned short* wlane = wb + (size_t)(w * 64 + tq) * 512 + qd * 8;

    const int atom = qd ^ ((tq >> 1) & 3);
    const int xoff = tq * 32 + atom * 8;

    f32x4 acc[4][4];
#pragma unroll
    for (int a = 0; a < 4; ++a)
#pragma unroll
        for (int b = 0; b < 4; ++b) acc[a][b] = (f32x4){0.f, 0.f, 0.f, 0.f};

    // prologue: stage chunk 0 into buf 0
    GLDS16(gsrc[0], &smem[(size_t)tid * 8]);
    GLDS16(gsrc[1], &smem[(size_t)(256 + tid) * 8]);
    if (tid < 128) GLDS16(gsrc[2], &smem[(size_t)(512 + tid) * 8]);

#pragma unroll
    for (int c = 0; c < 8; ++c) {
        const int b = c & 1;
        __syncthreads();   // buf b ready (vmcnt0 drains glds(c)); prev reads done

        // W for both sub-chunks FIRST (so their use waits only vmcnt(3))
        bf16x8_t Wf0[12], Wf1[12];
#pragma unroll
        for (int cs = 0; cs < 4; ++cs)
#pragma unroll
            for (int kk = 0; kk < 3; ++kk) {
                const unsigned short* p = wlane + (size_t)(kk * 256 + cs * 16) * 512 + c * 64;
                Wf0[cs * 3 + kk] = *(const bf16x8_t*)p;
                Wf1[cs * 3 + kk] = *(const bf16x8_t*)(p + 32);
            }
        // prefetch chunk c+1 into buf b^1 (stays in flight through the MFMAs)
        if (c < 7) {
            const int bo = (b ^ 1) * 5120;
            GLDS16(gsrc[0] + (c + 1) * 64, &smem[bo + (size_t)tid * 8]);
            GLDS16(gsrc[1] + (c + 1) * 64, &smem[bo + (size_t)(256 + tid) * 8]);
            if (tid < 128) GLDS16(gsrc[2] + (c + 1) * 64, &smem[bo + (size_t)(512 + tid) * 8]);
        }

        // sub-chunk 0
        {
            const int plane = b * 5120;
            bf16x8_t Xf[9];
#pragma unroll
            for (int m = 0; m < 9; ++m)
                Xf[m] = *(const bf16x8_t*)&smem[plane + m * 256 + xoff];
#pragma unroll
            for (int cs = 0; cs < 4; ++cs)
#pragma unroll
                for (int kk = 0; kk < 3; ++kk)
#pragma unroll
                    for (int ts = 0; ts < 4; ++ts)
                        acc[ts][cs] = __builtin_amdgcn_mfma_f32_16x16x32_bf16(
                            Xf[2 * ts + kk], Wf0[cs * 3 + kk], acc[ts][cs], 0, 0, 0);
        }
        // sub-chunk 1
        {
            const int plane = b * 5120 + 2560;
            bf16x8_t Xf[9];
#pragma unroll
            for (int m = 0; m < 9; ++m)
                Xf[m] = *(const bf16x8_t*)&smem[plane + m * 256 + xoff];
#pragma unroll
            for (int cs = 0; cs < 4; ++cs)
#pragma unroll
                for (int kk = 0; kk < 3; ++kk)
#pragma unroll
                    for (int ts = 0; ts < 4; ++ts)
                        acc[ts][cs] = __builtin_amdgcn_mfma_f32_16x16x32_bf16(
                            Xf[2 * ts + kk], Wf1[cs * 3 + kk], acc[ts][cs], 0, 0, 0);
        }
    }

    // epilogue: bn + relu -> bf16 -> 4-pass LDS transpose (16 t-rows per pass)
    float iv[4], sh[4];
#pragma unroll
    for (int cs = 0; cs < 4; ++cs) {
        int co = w * 64 + cs * 16 + tq;
        iv[cs] = g[co] / sqrtf(vr[co] + 1e-5f);
        sh[cs] = be[co] - mn[co] * iv[cs];
    }
    unsigned short* us1 = smem;   // 16*264 = 4224 ushort, fits in staging space
    const int row = tid >> 4, seg = tid & 15;
#pragma unroll
    for (int p = 0; p < 4; ++p) {
        __syncthreads();
#pragma unroll
        for (int cs = 0; cs < 4; ++cs) {
            int co = w * 64 + cs * 16 + tq;
#pragma unroll
            for (int rg = 0; rg < 4; ++rg)
                us1[(qd * 4 + rg) * 264 + co] =
                    f2bf(fmaxf(fmaf(acc[p][cs][rg], iv[cs], sh[cs]), 0.0f));
        }
        __syncthreads();
        unsigned short* yp = y1t + ((size_t)n * 1024 + t0 + p * 16 + row) * 256 + seg * 16;
        *(uint4*)yp       = *(const uint4*)&us1[row * 264 + seg * 16];
        *(uint4*)(yp + 8) = *(const uint4*)&us1[row * 264 + seg * 16 + 8];
    }
}

// ---------------------------------------------------------------------------
// K2: upsample2(y1t) -> conv2 (256->32, d=16) + bn2 + relu via bf16 MFMA.
// Output TRANSPOSED fp32: y2t[n][2048t][32co].  (unchanged)
__global__ __launch_bounds__(256, 2) void k2_mfma(
    const unsigned short* __restrict__ y1t, const unsigned short* __restrict__ w2b,
    const float* __restrict__ g, const float* __restrict__ be,
    const float* __restrict__ mn, const float* __restrict__ vr,
    float* __restrict__ y2t)
{
    const int tid  = threadIdx.x;
    const int lane = tid & 63;
    const int w    = tid >> 6;
    const int tq   = lane & 15;
    const int qd   = lane >> 4;
    const int t0   = blockIdx.x * 256;
    const int n    = blockIdx.y;

    __shared__ union SM {
        unsigned short us[288 * 40];
        float tr[256 * 36];
    } sm;

    f32x4 acc[4][2];
#pragma unroll
    for (int a = 0; a < 4; ++a)
#pragma unroll
        for (int b = 0; b < 2; ++b) acc[a][b] = (f32x4){0.f, 0.f, 0.f, 0.f};

    const unsigned short* yn = y1t + (size_t)n * 1024 * 256;

    for (int ch = 0; ch < 8; ++ch) {
        const int ci0 = ch * 32;
        __syncthreads();
        for (int idx = tid; idx < 1152; idx += 256) {
            int r = idx >> 2, gq = idx & 3;
            int u = reflect_idx(t0 - 16 + r, 2048);
            float src = fmaxf((float)u * 0.5f - 0.25f, 0.0f);
            int i0 = (int)src;
            float wl = src - (float)i0;
            int i1 = i0 + 1 > 1023 ? 1023 : i0 + 1;
            const unsigned short* p0 = yn + (size_t)i0 * 256 + ci0 + gq * 8;
            const unsigned short* p1 = yn + (size_t)i1 * 256 + ci0 + gq * 8;
            uint4 ua = *(const uint4*)p0;
            uint4 ub = *(const uint4*)p1;
            const unsigned short* sa = (const unsigned short*)&ua;
            const unsigned short* sb = (const unsigned short*)&ub;
            unsigned short pk[8];
#pragma unroll
            for (int j = 0; j < 8; ++j) {
                float a = bf2f(sa[j]);
                float b = bf2f(sb[j]);
                pk[j] = f2bf(a + wl * (b - a));
            }
            *(uint4*)&sm.us[r * 40 + gq * 8] = *(const uint4*)pk;
        }
        __syncthreads();

        bf16x8_t Bf[2][3];
#pragma unroll
        for (int cs = 0; cs < 2; ++cs)
#pragma unroll
            for (int kk = 0; kk < 3; ++kk)
                Bf[cs][kk] = *(const bf16x8_t*)(w2b +
                    ((size_t)(kk * 32 + cs * 16 + tq)) * 256 + ci0 + qd * 8);

        bf16x8_t Af[6];
#pragma unroll
        for (int s = 0; s < 6; ++s)
            Af[s] = *(const bf16x8_t*)&sm.us[(w * 64 + s * 16 + tq) * 40 + qd * 8];

#pragma unroll
        for (int ts = 0; ts < 4; ++ts)
#pragma unroll
            for (int cs = 0; cs < 2; ++cs)
#pragma unroll
                for (int kk = 0; kk < 3; ++kk)
                    acc[ts][cs] = __builtin_amdgcn_mfma_f32_16x16x32_bf16(
                        Af[ts + kk], Bf[cs][kk], acc[ts][cs], 0, 0, 0);
    }

    __syncthreads();
#pragma unroll
    for (int cs = 0; cs < 2; ++cs) {
        int co = cs * 16 + tq;
        float iv = g[co] / sqrtf(vr[co] + 1e-5f);
        float sh = be[co] - mn[co] * iv;
#pragma unroll
        for (int ts = 0; ts < 4; ++ts)
#pragma unroll
            for (int rg = 0; rg < 4; ++rg) {
                int tl = w * 64 + ts * 16 + qd * 4 + rg;
                sm.tr[tl * 36 + co] = fmaxf(fmaf(acc[ts][cs][rg], iv, sh), 0.0f);
            }
    }
    __syncthreads();
    float* yo = y2t + ((size_t)n * 2048 + t0 + tid) * 32;
#pragma unroll
    for (int j = 0; j < 8; ++j)
        *(float4*)(yo + j * 4) = *(const float4*)&sm.tr[tid * 36 + j * 4];
}

// ---------------------------------------------------------------------------
// K3: upsample2(y2t) -> conv3 (32->3, d=32) + bias, transposed store (unchanged)
__global__ __launch_bounds__(256, 2) void k3_out(
    const float* __restrict__ y2t, const float* __restrict__ w3,
    const float* __restrict__ bias, float* __restrict__ out)
{
    const int tid = threadIdx.x;
    const int t0 = blockIdx.x * 256;
    const int n  = blockIdx.y;

    __shared__ float us[32 * 321];
    __shared__ float wsh[288];

    for (int idx = tid; idx < 288; idx += 256) wsh[idx] = w3[idx];

    const float* yn = y2t + (size_t)n * 2048 * 32;
    for (int idx = tid; idx < 1280; idx += 256) {
        int r = idx >> 2, gq = idx & 3;
        int u = reflect_idx(t0 - 32 + r, 4096);
        float src = fmaxf((float)u * 0.5f - 0.25f, 0.0f);
        int i0 = (int)src;
        float wl = src - (float)i0;
        int i1 = i0 + 1 > 2047 ? 2047 : i0 + 1;
        const float* p0 = yn + (size_t)i0 * 32 + gq * 8;
        const float* p1 = yn + (size_t)i1 * 32 + gq * 8;
        float4 a0 = *(const float4*)p0;
        float4 a1 = *(const float4*)(p0 + 4);
        float4 b0 = *(const float4*)p1;
        float4 b1 = *(const float4*)(p1 + 4);
        float v[8];
        v[0] = a0.x + wl * (b0.x - a0.x); v[1] = a0.y + wl * (b0.y - a0.y);
        v[2] = a0.z + wl * (b0.z - a0.z); v[3] = a0.w + wl * (b0.w - a0.w);
        v[4] = a1.x + wl * (b1.x - a1.x); v[5] = a1.y + wl * (b1.y - a1.y);
        v[6] = a1.z + wl * (b1.z - a1.z); v[7] = a1.w + wl * (b1.w - a1.w);
#pragma unroll
        for (int j = 0; j < 8; ++j)
            us[(gq * 8 + j) * 321 + r] = v[j];
    }
    __syncthreads();

    float a0 = 0.0f, a1 = 0.0f, a2 = 0.0f;
#pragma unroll 8
    for (int ci = 0; ci < 32; ++ci) {
        float x0 = us[ci * 321 + tid];
        float x1 = us[ci * 321 + tid + 32];
        float x2 = us[ci * 321 + tid + 64];
        a0 = fmaf(wsh[(0 * 32 + ci) * 3 + 0], x0, a0);
        a0 = fmaf(wsh[(0 * 32 + ci) * 3 + 1], x1, a0);
        a0 = fmaf(wsh[(0 * 32 + ci) * 3 + 2], x2, a0);
        a1 = fmaf(wsh[(1 * 32 + ci) * 3 + 0], x0, a1);
        a1 = fmaf(wsh[(1 * 32 + ci) * 3 + 1], x1, a1);
        a1 = fmaf(wsh[(1 * 32 + ci) * 3 + 2], x2, a1);
        a2 = fmaf(wsh[(2 * 32 + ci) * 3 + 0], x0, a2);
        a2 = fmaf(wsh[(2 * 32 + ci) * 3 + 1], x1, a2);
        a2 = fmaf(wsh[(2 * 32 + ci) * 3 + 2], x2, a2);
    }
    int b = n >> 2, s = n & 3;
    int t = t0 + tid;
    size_t ob = ((size_t)(b * 3) * 4096 + t) * 4 + s;
    out[ob]         = a0 + bias[0];
    out[ob + 16384] = a1 + bias[1];
    out[ob + 32768] = a2 + bias[2];
}

// ---------------------------------------------------------------------------
__global__ void k4a_valid(const float* __restrict__ tg, float* lacc) {
    __shared__ int flag;
    if (threadIdx.x == 0) flag = 0;
    __syncthreads();
    int b = blockIdx.x >> 2, s = blockIdx.x & 3;
    bool any = false;
    for (int idx = threadIdx.x; idx < 3 * 4096; idx += 256) {
        int c = idx >> 12, t = idx & 4095;
        float v = tg[((size_t)(b * 3 + c) * 4096 + t) * 4 + s];
        any |= (v != 0.0f);
    }
    if (any) flag = 1;
    __syncthreads();
    if (threadIdx.x == 0 && flag) atomicAdd((int*)(lacc + 1), 1);
}

__global__ __launch_bounds__(256) void k4b_ce(
    const float* __restrict__ x, const float* __restrict__ tg, float* lacc)
{
    int i = blockIdx.x * 256 + threadIdx.x;
    int s = i & 3;
    int t = (i >> 2) & 4095;
    int b = i >> 14;
    size_t base = ((size_t)(b * 3) * 4096 + t) * 4 + s;
    float x0 = x[base], x1 = x[base + 16384], x2 = x[base + 32768];
    float mx = fmaxf(x0, fmaxf(x1, x2));
    float e0 = expf(x0 - mx), e1 = expf(x1 - mx), e2 = expf(x2 - mx);
    float lse = mx + logf(e0 + e1 + e2);
    float g0 = tg[base], g1 = tg[base + 16384], g2 = tg[base + 32768];
    float v = g0 * (lse - x0) + g1 * (lse - x1) + g2 * (lse - x2);

    for (int off = 32; off > 0; off >>= 1) v += __shfl_down(v, off);
    __shared__ float wsum[4];
    int lane = threadIdx.x & 63, wid = threadIdx.x >> 6;
    if (lane == 0) wsum[wid] = v;
    __syncthreads();
    if (threadIdx.x == 0) {
        atomicAdd(lacc, wsum[0] + wsum[1] + wsum[2] + wsum[3]);
    }
}

__global__ void k4c_final(const float* lacc, float* out) {
    if (threadIdx.x == 0) {
        float sum = lacc[0];
        int num = ((const int*)lacc)[1];
        out[786432] = sum / ((float)num * 4096.0f);
    }
}

// ---------------------------------------------------------------------------
extern "C" void kernel_launch(void* const* d_in, const int* in_sizes, int n_in,
                              void* d_out, int out_size, void* d_ws, size_t ws_size,
                              hipStream_t stream) {
    (void)in_sizes; (void)n_in; (void)out_size;
    const float* fusion  = (const float*)d_in[0];
    const float* targets = (const float*)d_in[1];
    const float* w1  = (const float*)d_in[2];
    const float* g1  = (const float*)d_in[3];
    const float* be1 = (const float*)d_in[4];
    const float* mn1 = (const float*)d_in[5];
    const float* vr1 = (const float*)d_in[6];
    const float* w2  = (const float*)d_in[7];
    const float* g2  = (const float*)d_in[8];
    const float* be2 = (const float*)d_in[9];
    const float* mn2 = (const float*)d_in[10];
    const float* vr2 = (const float*)d_in[11];
    const float* w3  = (const float*)d_in[12];
    const float* b3  = (const float*)d_in[13];
    float* out = (float*)d_out;

    char* ws = (char*)d_ws;
    unsigned short* y1t = (unsigned short*)ws;              // 33,554,432 B
    unsigned short* xb  = (unsigned short*)(ws + 33554432); // 16 or 64 MB
    float* y2t = (float*)(ws + 33554432);                   // 16 MB, aliases xb

    const bool single = ws_size >= 101500000ull;
    size_t woff = single ? (33554432ull + 67108864ull) : (33554432ull + 16777216ull);
    unsigned short* wb  = (unsigned short*)(ws + woff);            // 786,432 B
    unsigned short* w2b = (unsigned short*)(ws + woff + 786432);   //  49,152 B
    float* lacc = (float*)(ws + woff + 786432 + 49152);            //     256 B

    k0_init<<<1, 64, 0, stream>>>(lacc);
    kw1b<<<1536, 256, 0, stream>>>(w1, wb);
    kw2b<<<96, 256, 0, stream>>>(w2, w2b);
    if (single) {
        kx_t<<<dim3(16, 8, 64), 256, 0, stream>>>(fusion, xb, 0);
        k1_mfma<<<dim3(16, 64), 256, 0, stream>>>(xb, wb, g1, be1, mn1, vr1, y1t, 0);
    } else {
        for (int r = 0; r < 4; ++r) {
            kx_t<<<dim3(16, 8, 16), 256, 0, stream>>>(fusion, xb, r * 16);
            k1_mfma<<<dim3(16, 16), 256, 0, stream>>>(xb, wb, g1, be1, mn1, vr1, y1t, r * 16);
        }
    }
    k2_mfma<<<dim3(8, 64), 256, 0, stream>>>(y1t, w2b, g2, be2, mn2, vr2, y2t);
    k3_out<<<dim3(16, 64), 256, 0, stream>>>(y2t, w3, b3, out);
    k4a_valid<<<64, 256, 0, stream>>>(targets, lacc);
    k4b_ce<<<1024, 256, 0, stream>>>(out, targets, lacc);
    k4c_final<<<1, 64, 0, stream>>>(lacc, out);
}

// Round 6
// 376.008 us; speedup vs baseline: 1.2891x; 1.0992x over previous
//
#include <hip/hip_runtime.h>
#include <hip/hip_bf16.h>

#define DEV static __device__ __forceinline__

typedef short bf16x8_t __attribute__((ext_vector_type(8)));
typedef float f32x4 __attribute__((ext_vector_type(4)));

#define GLDS16(gp, lp) __builtin_amdgcn_global_load_lds( \
    (const __attribute__((address_space(1))) void*)(gp), \
    (__attribute__((address_space(3))) void*)(lp), 16, 0, 0)

DEV int reflect_idx(int q, int L) {
    q = q < 0 ? -q : q;
    q = q >= L ? 2 * L - 2 - q : q;
    return q;
}

DEV unsigned short f2bf(float f) {
    unsigned int b = __float_as_uint(f);
    unsigned int r = (b + 0x7FFFu + ((b >> 16) & 1u)) >> 16;
    return (unsigned short)r;
}
DEV float bf2f(unsigned short u) {
    return __uint_as_float(((unsigned int)u) << 16);
}

// ---------------------------------------------------------------------------
__global__ void k0_init(float* lacc) {
    if (threadIdx.x < 8) lacc[threadIdx.x] = 0.0f;
}

// prep: w1 [256co][512ci][3kk] fp32 -> wb [3kk][256co][512ci] bf16
__global__ void kw1b(const float* __restrict__ w1, unsigned short* __restrict__ wb) {
    int idx = blockIdx.x * 256 + threadIdx.x;   // 393216
    int kk = idx >> 17;
    int rem = idx & 131071;
    int co = rem >> 9;
    int ci = rem & 511;
    wb[idx] = f2bf(w1[(co * 512 + ci) * 3 + kk]);
}

// prep: w2 [32co][256ci][3kk] fp32 -> w2b [3kk][32co][256ci] bf16
__global__ void kw2b(const float* __restrict__ w2, unsigned short* __restrict__ w2b) {
    int idx = blockIdx.x * 256 + threadIdx.x;   // 24576 = kk*8192 + co*256 + ci
    int ci = idx & 255;
    int co = (idx >> 8) & 31;
    int kk = idx >> 13;
    w2b[idx] = f2bf(w2[(co * 256 + ci) * 3 + kk]);
}

// prep: transpose x[n][512ci][1024t] fp32 -> xb[nr][1024t][512ci] bf16
__global__ __launch_bounds__(256) void kx_t(const float* __restrict__ x,
                                            unsigned short* __restrict__ xb, int n0) {
    __shared__ float ls[64][65];
    const int tid = threadIdx.x;
    const int t0 = blockIdx.x * 64, ci0 = blockIdx.y * 64;
    const int n = n0 + blockIdx.z;
    const float* xp = x + ((size_t)n * 512 + ci0) * 1024 + t0;
    for (int idx = tid; idx < 1024; idx += 256) {
        int r = idx >> 4, c4 = (idx & 15) * 4;
        float4 v = *(const float4*)(xp + r * 1024 + c4);
        ls[r][c4] = v.x; ls[r][c4 + 1] = v.y; ls[r][c4 + 2] = v.z; ls[r][c4 + 3] = v.w;
    }
    __syncthreads();
    unsigned short* xo = xb + ((size_t)blockIdx.z * 1024 + t0) * 512 + ci0;
#pragma unroll
    for (int p = 0; p < 2; ++p) {
        int trow = (tid >> 3) + p * 32;
        int cj = (tid & 7) * 8;
        unsigned short pk[8];
#pragma unroll
        for (int j = 0; j < 8; ++j) pk[j] = f2bf(ls[cj + j][trow]);
        *(uint4*)(xo + (size_t)trow * 512 + cj) = *(const uint4*)pk;
    }
}

// ---------------------------------------------------------------------------
// K1 v4 (m97 pattern): conv1 as implicit GEMM, bf16 MFMA 16x16x32.
// Block tile 128t x 128co (grid: 8 t-tiles, n, 2 co-tiles); 4 waves, each
// 64t x 64co (4x4 16x16 acc). K = [kk][ci] in 48 chunks of 32 ci; the kk tap
// shift (t + 8(kk-1), reflect) is applied when staging the A-tile.
// Per chunk: 4 glds (A 8KB + B 8KB, double-buffered, swizzled 64B rows),
// 1 barrier, 8 ds_read_b128 + 16 MFMA per wave. BOTH operands via LDS:
// register pressure stays low (R3/R5 kept W in VGPRs -> serialization).
__global__ __launch_bounds__(256, 2) void k1_mfma(
    const unsigned short* __restrict__ xb, const unsigned short* __restrict__ wb,
    const float* __restrict__ g, const float* __restrict__ be,
    const float* __restrict__ mn, const float* __restrict__ vr,
    unsigned short* __restrict__ y1t, int n0)
{
    const int tid  = threadIdx.x;
    const int lane = tid & 63;
    const int w    = tid >> 6;
    const int tw   = w >> 1;           // t-half of wave
    const int cw   = w & 1;            // co-half of wave
    const int tq   = lane & 15;
    const int qd   = lane >> 4;
    const int t0   = blockIdx.x * 128;
    const int nr   = blockIdx.y;
    const int n    = n0 + nr;
    const int cb   = blockIdx.z;       // co block (0/1): co = cb*128 + local

    __shared__ unsigned short smem[17408];  // staging 2x8192 ush; epi 128x136 ush

    // staging lane slots: l = slot*256 + tid; row rl = l>>2, q = l&3,
    // swizzle q' = q ^ ((rl>>1)&3)  (R5-verified zero-conflict scheme)
    const int rl0 = tid >> 2;
    const int rl1 = 64 + (tid >> 2);
    const int q0  = (tid & 3) ^ ((rl0 >> 1) & 3);
    const int q1  = (tid & 3) ^ ((rl1 >> 1) & 3);

    const unsigned short* xn = xb + (size_t)nr * 1024 * 512;
    // A row offsets (ushort) per kk: row = reflect(t0 + rl + 8*kk - 8)
    int aoff0[3], aoff1[3];
#pragma unroll
    for (int kk = 0; kk < 3; ++kk) {
        aoff0[kk] = reflect_idx(t0 + rl0 + 8 * kk - 8, 1024) * 512 + q0 * 8;
        aoff1[kk] = reflect_idx(t0 + rl1 + 8 * kk - 8, 1024) * 512 + q1 * 8;
    }
    // W row pointers (rows co = cb*128 + rl), kk stride = 256*512 ushorts
    const unsigned short* wp0 = wb + (size_t)(cb * 128 + rl0) * 512 + q0 * 8;
    const unsigned short* wp1 = wb + (size_t)(cb * 128 + rl1) * 512 + q1 * 8;

    // fragment read constants
    const int atom = qd ^ ((tq >> 1) & 3);

    f32x4 acc[4][4];
#pragma unroll
    for (int a = 0; a < 4; ++a)
#pragma unroll
        for (int b = 0; b < 4; ++b) acc[a][b] = (f32x4){0.f, 0.f, 0.f, 0.f};

    // prologue: stage chunk 0 into buf 0
    GLDS16(xn + aoff0[0], &smem[tid * 8]);
    GLDS16(xn + aoff1[0], &smem[2048 + tid * 8]);
    GLDS16(wp0, &smem[4096 + tid * 8]);
    GLDS16(wp1, &smem[6144 + tid * 8]);

#pragma unroll
    for (int c = 0; c < 48; ++c) {
        const int par = c & 1;
        __syncthreads();   // drains glds(c) (vmcnt0 before barrier)
        if (c < 47) {
            const int nc = c + 1, nk = nc >> 4, nj = nc & 15;
            const int bo = (par ^ 1) * 8192;
            GLDS16(xn + aoff0[nk] + nj * 32, &smem[bo + tid * 8]);
            GLDS16(xn + aoff1[nk] + nj * 32, &smem[bo + 2048 + tid * 8]);
            GLDS16(wp0 + (size_t)nk * 131072 + nj * 32, &smem[bo + 4096 + tid * 8]);
            GLDS16(wp1 + (size_t)nk * 131072 + nj * 32, &smem[bo + 6144 + tid * 8]);
        }
        const int ab = par * 8192;
        const int bb = par * 8192 + 4096;
        bf16x8_t Af[4], Bf[4];
#pragma unroll
        for (int ts = 0; ts < 4; ++ts)
            Af[ts] = *(const bf16x8_t*)&smem[ab + (tw * 64 + ts * 16 + tq) * 32 + atom * 8];
#pragma unroll
        for (int cs = 0; cs < 4; ++cs)
            Bf[cs] = *(const bf16x8_t*)&smem[bb + (cw * 64 + cs * 16 + tq) * 32 + atom * 8];
#pragma unroll
        for (int ts = 0; ts < 4; ++ts)
#pragma unroll
            for (int cs = 0; cs < 4; ++cs)
                acc[ts][cs] = __builtin_amdgcn_mfma_f32_16x16x32_bf16(
                    Af[ts], Bf[cs], acc[ts][cs], 0, 0, 0);
    }

    // epilogue: bn + relu -> bf16 -> LDS transpose us[128t][128co] (stride 136)
    __syncthreads();   // all waves done reading staging bufs
#pragma unroll
    for (int cs = 0; cs < 4; ++cs) {
        int col = cw * 64 + cs * 16 + tq;
        int co  = cb * 128 + col;
        float iv = g[co] / sqrtf(vr[co] + 1e-5f);
        float sh = be[co] - mn[co] * iv;
#pragma unroll
        for (int ts = 0; ts < 4; ++ts)
#pragma unroll
            for (int rg = 0; rg < 4; ++rg)
                smem[(tw * 64 + ts * 16 + qd * 4 + rg) * 136 + col] =
                    f2bf(fmaxf(fmaf(acc[ts][cs][rg], iv, sh), 0.0f));
    }
    __syncthreads();
    const int srow = tid >> 4, sseg = tid & 15;
#pragma unroll
    for (int p = 0; p < 8; ++p) {
        int row = p * 16 + srow;
        unsigned short* yp = y1t + ((size_t)n * 1024 + t0 + row) * 256 + cb * 128 + sseg * 8;
        *(uint4*)yp = *(const uint4*)&smem[row * 136 + sseg * 8];
    }
}

// ---------------------------------------------------------------------------
// K2: upsample2(y1t) -> conv2 (256->32, d=16) + bn2 + relu via bf16 MFMA.
// Output TRANSPOSED fp32: y2t[n][2048t][32co].  (unchanged)
__global__ __launch_bounds__(256, 2) void k2_mfma(
    const unsigned short* __restrict__ y1t, const unsigned short* __restrict__ w2b,
    const float* __restrict__ g, const float* __restrict__ be,
    const float* __restrict__ mn, const float* __restrict__ vr,
    float* __restrict__ y2t)
{
    const int tid  = threadIdx.x;
    const int lane = tid & 63;
    const int w    = tid >> 6;
    const int tq   = lane & 15;
    const int qd   = lane >> 4;
    const int t0   = blockIdx.x * 256;
    const int n    = blockIdx.y;

    __shared__ union SM {
        unsigned short us[288 * 40];
        float tr[256 * 36];
    } sm;

    f32x4 acc[4][2];
#pragma unroll
    for (int a = 0; a < 4; ++a)
#pragma unroll
        for (int b = 0; b < 2; ++b) acc[a][b] = (f32x4){0.f, 0.f, 0.f, 0.f};

    const unsigned short* yn = y1t + (size_t)n * 1024 * 256;

    for (int ch = 0; ch < 8; ++ch) {
        const int ci0 = ch * 32;
        __syncthreads();
        for (int idx = tid; idx < 1152; idx += 256) {
            int r = idx >> 2, gq = idx & 3;
            int u = reflect_idx(t0 - 16 + r, 2048);
            float src = fmaxf((float)u * 0.5f - 0.25f, 0.0f);
            int i0 = (int)src;
            float wl = src - (float)i0;
            int i1 = i0 + 1 > 1023 ? 1023 : i0 + 1;
            const unsigned short* p0 = yn + (size_t)i0 * 256 + ci0 + gq * 8;
            const unsigned short* p1 = yn + (size_t)i1 * 256 + ci0 + gq * 8;
            uint4 ua = *(const uint4*)p0;
            uint4 ub = *(const uint4*)p1;
            const unsigned short* sa = (const unsigned short*)&ua;
            const unsigned short* sb = (const unsigned short*)&ub;
            unsigned short pk[8];
#pragma unroll
            for (int j = 0; j < 8; ++j) {
                float a = bf2f(sa[j]);
                float b = bf2f(sb[j]);
                pk[j] = f2bf(a + wl * (b - a));
            }
            *(uint4*)&sm.us[r * 40 + gq * 8] = *(const uint4*)pk;
        }
        __syncthreads();

        bf16x8_t Bf[2][3];
#pragma unroll
        for (int cs = 0; cs < 2; ++cs)
#pragma unroll
            for (int kk = 0; kk < 3; ++kk)
                Bf[cs][kk] = *(const bf16x8_t*)(w2b +
                    ((size_t)(kk * 32 + cs * 16 + tq)) * 256 + ci0 + qd * 8);

        bf16x8_t Af[6];
#pragma unroll
        for (int s = 0; s < 6; ++s)
            Af[s] = *(const bf16x8_t*)&sm.us[(w * 64 + s * 16 + tq) * 40 + qd * 8];

#pragma unroll
        for (int ts = 0; ts < 4; ++ts)
#pragma unroll
            for (int cs = 0; cs < 2; ++cs)
#pragma unroll
                for (int kk = 0; kk < 3; ++kk)
                    acc[ts][cs] = __builtin_amdgcn_mfma_f32_16x16x32_bf16(
                        Af[ts + kk], Bf[cs][kk], acc[ts][cs], 0, 0, 0);
    }

    __syncthreads();
#pragma unroll
    for (int cs = 0; cs < 2; ++cs) {
        int co = cs * 16 + tq;
        float iv = g[co] / sqrtf(vr[co] + 1e-5f);
        float sh = be[co] - mn[co] * iv;
#pragma unroll
        for (int ts = 0; ts < 4; ++ts)
#pragma unroll
            for (int rg = 0; rg < 4; ++rg) {
                int tl = w * 64 + ts * 16 + qd * 4 + rg;
                sm.tr[tl * 36 + co] = fmaxf(fmaf(acc[ts][cs][rg], iv, sh), 0.0f);
            }
    }
    __syncthreads();
    float* yo = y2t + ((size_t)n * 2048 + t0 + tid) * 32;
#pragma unroll
    for (int j = 0; j < 8; ++j)
        *(float4*)(yo + j * 4) = *(const float4*)&sm.tr[tid * 36 + j * 4];
}

// ---------------------------------------------------------------------------
// K3: upsample2(y2t) -> conv3 (32->3, d=32) + bias, transposed store (unchanged)
__global__ __launch_bounds__(256, 2) void k3_out(
    const float* __restrict__ y2t, const float* __restrict__ w3,
    const float* __restrict__ bias, float* __restrict__ out)
{
    const int tid = threadIdx.x;
    const int t0 = blockIdx.x * 256;
    const int n  = blockIdx.y;

    __shared__ float us[32 * 321];
    __shared__ float wsh[288];

    for (int idx = tid; idx < 288; idx += 256) wsh[idx] = w3[idx];

    const float* yn = y2t + (size_t)n * 2048 * 32;
    for (int idx = tid; idx < 1280; idx += 256) {
        int r = idx >> 2, gq = idx & 3;
        int u = reflect_idx(t0 - 32 + r, 4096);
        float src = fmaxf((float)u * 0.5f - 0.25f, 0.0f);
        int i0 = (int)src;
        float wl = src - (float)i0;
        int i1 = i0 + 1 > 2047 ? 2047 : i0 + 1;
        const float* p0 = yn + (size_t)i0 * 32 + gq * 8;
        const float* p1 = yn + (size_t)i1 * 32 + gq * 8;
        float4 a0 = *(const float4*)p0;
        float4 a1 = *(const float4*)(p0 + 4);
        float4 b0 = *(const float4*)p1;
        float4 b1 = *(const float4*)(p1 + 4);
        float v[8];
        v[0] = a0.x + wl * (b0.x - a0.x); v[1] = a0.y + wl * (b0.y - a0.y);
        v[2] = a0.z + wl * (b0.z - a0.z); v[3] = a0.w + wl * (b0.w - a0.w);
        v[4] = a1.x + wl * (b1.x - a1.x); v[5] = a1.y + wl * (b1.y - a1.y);
        v[6] = a1.z + wl * (b1.z - a1.z); v[7] = a1.w + wl * (b1.w - a1.w);
#pragma unroll
        for (int j = 0; j < 8; ++j)
            us[(gq * 8 + j) * 321 + r] = v[j];
    }
    __syncthreads();

    float a0 = 0.0f, a1 = 0.0f, a2 = 0.0f;
#pragma unroll 8
    for (int ci = 0; ci < 32; ++ci) {
        float x0 = us[ci * 321 + tid];
        float x1 = us[ci * 321 + tid + 32];
        float x2 = us[ci * 321 + tid + 64];
        a0 = fmaf(wsh[(0 * 32 + ci) * 3 + 0], x0, a0);
        a0 = fmaf(wsh[(0 * 32 + ci) * 3 + 1], x1, a0);
        a0 = fmaf(wsh[(0 * 32 + ci) * 3 + 2], x2, a0);
        a1 = fmaf(wsh[(1 * 32 + ci) * 3 + 0], x0, a1);
        a1 = fmaf(wsh[(1 * 32 + ci) * 3 + 1], x1, a1);
        a1 = fmaf(wsh[(1 * 32 + ci) * 3 + 2], x2, a1);
        a2 = fmaf(wsh[(2 * 32 + ci) * 3 + 0], x0, a2);
        a2 = fmaf(wsh[(2 * 32 + ci) * 3 + 1], x1, a2);
        a2 = fmaf(wsh[(2 * 32 + ci) * 3 + 2], x2, a2);
    }
    int b = n >> 2, s = n & 3;
    int t = t0 + tid;
    size_t ob = ((size_t)(b * 3) * 4096 + t) * 4 + s;
    out[ob]         = a0 + bias[0];
    out[ob + 16384] = a1 + bias[1];
    out[ob + 32768] = a2 + bias[2];
}

// ---------------------------------------------------------------------------
__global__ void k4a_valid(const float* __restrict__ tg, float* lacc) {
    __shared__ int flag;
    if (threadIdx.x == 0) flag = 0;
    __syncthreads();
    int b = blockIdx.x >> 2, s = blockIdx.x & 3;
    bool any = false;
    for (int idx = threadIdx.x; idx < 3 * 4096; idx += 256) {
        int c = idx >> 12, t = idx & 4095;
        float v = tg[((size_t)(b * 3 + c) * 4096 + t) * 4 + s];
        any |= (v != 0.0f);
    }
    if (any) flag = 1;
    __syncthreads();
    if (threadIdx.x == 0 && flag) atomicAdd((int*)(lacc + 1), 1);
}

__global__ __launch_bounds__(256) void k4b_ce(
    const float* __restrict__ x, const float* __restrict__ tg, float* lacc)
{
    int i = blockIdx.x * 256 + threadIdx.x;
    int s = i & 3;
    int t = (i >> 2) & 4095;
    int b = i >> 14;
    size_t base = ((size_t)(b * 3) * 4096 + t) * 4 + s;
    float x0 = x[base], x1 = x[base + 16384], x2 = x[base + 32768];
    float mx = fmaxf(x0, fmaxf(x1, x2));
    float e0 = expf(x0 - mx), e1 = expf(x1 - mx), e2 = expf(x2 - mx);
    float lse = mx + logf(e0 + e1 + e2);
    float g0 = tg[base], g1 = tg[base + 16384], g2 = tg[base + 32768];
    float v = g0 * (lse - x0) + g1 * (lse - x1) + g2 * (lse - x2);

    for (int off = 32; off > 0; off >>= 1) v += __shfl_down(v, off);
    __shared__ float wsum[4];
    int lane = threadIdx.x & 63, wid = threadIdx.x >> 6;
    if (lane == 0) wsum[wid] = v;
    __syncthreads();
    if (threadIdx.x == 0) {
        atomicAdd(lacc, wsum[0] + wsum[1] + wsum[2] + wsum[3]);
    }
}

__global__ void k4c_final(const float* lacc, float* out) {
    if (threadIdx.x == 0) {
        float sum = lacc[0];
        int num = ((const int*)lacc)[1];
        out[786432] = sum / ((float)num * 4096.0f);
    }
}

// ---------------------------------------------------------------------------
extern "C" void kernel_launch(void* const* d_in, const int* in_sizes, int n_in,
                              void* d_out, int out_size, void* d_ws, size_t ws_size,
                              hipStream_t stream) {
    (void)in_sizes; (void)n_in; (void)out_size;
    const float* fusion  = (const float*)d_in[0];
    const float* targets = (const float*)d_in[1];
    const float* w1  = (const float*)d_in[2];
    const float* g1  = (const float*)d_in[3];
    const float* be1 = (const float*)d_in[4];
    const float* mn1 = (const float*)d_in[5];
    const float* vr1 = (const float*)d_in[6];
    const float* w2  = (const float*)d_in[7];
    const float* g2  = (const float*)d_in[8];
    const float* be2 = (const float*)d_in[9];
    const float* mn2 = (const float*)d_in[10];
    const float* vr2 = (const float*)d_in[11];
    const float* w3  = (const float*)d_in[12];
    const float* b3  = (const float*)d_in[13];
    float* out = (float*)d_out;

    char* ws = (char*)d_ws;
    unsigned short* y1t = (unsigned short*)ws;              // 33,554,432 B
    unsigned short* xb  = (unsigned short*)(ws + 33554432); // 16 or 64 MB
    float* y2t = (float*)(ws + 33554432);                   // 16 MB, aliases xb

    const bool single = ws_size >= 101500000ull;
    size_t woff = single ? (33554432ull + 67108864ull) : (33554432ull + 16777216ull);
    unsigned short* wb  = (unsigned short*)(ws + woff);            // 786,432 B
    unsigned short* w2b = (unsigned short*)(ws + woff + 786432);   //  49,152 B
    float* lacc = (float*)(ws + woff + 786432 + 49152);            //     256 B

    k0_init<<<1, 64, 0, stream>>>(lacc);
    kw1b<<<1536, 256, 0, stream>>>(w1, wb);
    kw2b<<<96, 256, 0, stream>>>(w2, w2b);
    if (single) {
        kx_t<<<dim3(16, 8, 64), 256, 0, stream>>>(fusion, xb, 0);
        k1_mfma<<<dim3(8, 64, 2), 256, 0, stream>>>(xb, wb, g1, be1, mn1, vr1, y1t, 0);
    } else {
        for (int r = 0; r < 4; ++r) {
            kx_t<<<dim3(16, 8, 16), 256, 0, stream>>>(fusion, xb, r * 16);
            k1_mfma<<<dim3(8, 16, 2), 256, 0, stream>>>(xb, wb, g1, be1, mn1, vr1, y1t, r * 16);
        }
    }
    k2_mfma<<<dim3(8, 64), 256, 0, stream>>>(y1t, w2b, g2, be2, mn2, vr2, y2t);
    k3_out<<<dim3(16, 64), 256, 0, stream>>>(y2t, w3, b3, out);
    k4a_valid<<<64, 256, 0, stream>>>(targets, lacc);
    k4b_ce<<<1024, 256, 0, stream>>>(out, targets, lacc);
    k4c_final<<<1, 64, 0, stream>>>(lacc, out);
}

// Round 7
// 359.887 us; speedup vs baseline: 1.3469x; 1.0448x over previous
//
#include <hip/hip_runtime.h>
#include <hip/hip_bf16.h>

#define DEV static __device__ __forceinline__

typedef short bf16x8_t __attribute__((ext_vector_type(8)));
typedef float f32x4 __attribute__((ext_vector_type(4)));

#define GLDS16(gp, lp) __builtin_amdgcn_global_load_lds( \
    (const __attribute__((address_space(1))) void*)(gp), \
    (__attribute__((address_space(3))) void*)(lp), 16, 0, 0)

DEV int reflect_idx(int q, int L) {
    q = q < 0 ? -q : q;
    q = q >= L ? 2 * L - 2 - q : q;
    return q;
}

DEV unsigned short f2bf(float f) {
    unsigned int b = __float_as_uint(f);
    unsigned int r = (b + 0x7FFFu + ((b >> 16) & 1u)) >> 16;
    return (unsigned short)r;
}
DEV float bf2f(unsigned short u) {
    return __uint_as_float(((unsigned int)u) << 16);
}

// ---------------------------------------------------------------------------
// fused prep: w1 -> wb [3kk][256co][512ci] bf16; w2 -> w2b [3kk][32co][256ci];
// zero loss accumulators (lacc[0..127])
__global__ void kprep(const float* __restrict__ w1, const float* __restrict__ w2,
                      unsigned short* __restrict__ wb, unsigned short* __restrict__ w2b,
                      float* lacc) {
    int idx = blockIdx.x * 256 + threadIdx.x;
    if (idx < 393216) {
        int kk = idx >> 17;
        int rem = idx & 131071;
        int co = rem >> 9;
        int ci = rem & 511;
        wb[idx] = f2bf(w1[(co * 512 + ci) * 3 + kk]);
    } else if (idx < 417792) {
        int j = idx - 393216;
        int ci = j & 255;
        int co = (j >> 8) & 31;
        int kk = j >> 13;
        w2b[j] = f2bf(w2[(co * 256 + ci) * 3 + kk]);
    }
    if (idx < 128) lacc[idx] = 0.0f;
}

// prep: transpose x[n][512ci][1024t] fp32 -> xb[nr][1024t][512ci] bf16
__global__ __launch_bounds__(256) void kx_t(const float* __restrict__ x,
                                            unsigned short* __restrict__ xb, int n0) {
    __shared__ float ls[64][65];
    const int tid = threadIdx.x;
    const int t0 = blockIdx.x * 64, ci0 = blockIdx.y * 64;
    const int n = n0 + blockIdx.z;
    const float* xp = x + ((size_t)n * 512 + ci0) * 1024 + t0;
    for (int idx = tid; idx < 1024; idx += 256) {
        int r = idx >> 4, c4 = (idx & 15) * 4;
        float4 v = *(const float4*)(xp + r * 1024 + c4);
        ls[r][c4] = v.x; ls[r][c4 + 1] = v.y; ls[r][c4 + 2] = v.z; ls[r][c4 + 3] = v.w;
    }
    __syncthreads();
    unsigned short* xo = xb + ((size_t)blockIdx.z * 1024 + t0) * 512 + ci0;
#pragma unroll
    for (int p = 0; p < 2; ++p) {
        int trow = (tid >> 3) + p * 32;
        int cj = (tid & 7) * 8;
        unsigned short pk[8];
#pragma unroll
        for (int j = 0; j < 8; ++j) pk[j] = f2bf(ls[cj + j][trow]);
        *(uint4*)(xo + (size_t)trow * 512 + cj) = *(const uint4*)pk;
    }
}

// ---------------------------------------------------------------------------
// K1 v5: R6's m97-pattern implicit GEMM with BK=64 intervals.
// Block tile 128t x 128co; 24 K-intervals of 64 ci (2 planes of 32), LDS
// double-buffered (2 x 32KB = 64KB), 8 glds + 1 barrier + 32 MFMA/wave per
// interval. kk tap shift applied at staging (reflect). Epilogue aliases LDS.
__global__ __launch_bounds__(256, 2) void k1_mfma(
    const unsigned short* __restrict__ xb, const unsigned short* __restrict__ wb,
    const float* __restrict__ g, const float* __restrict__ be,
    const float* __restrict__ mn, const float* __restrict__ vr,
    unsigned short* __restrict__ y1t, int n0)
{
    const int tid  = threadIdx.x;
    const int lane = tid & 63;
    const int w    = tid >> 6;
    const int tw   = w >> 1;
    const int cw   = w & 1;
    const int tq   = lane & 15;
    const int qd   = lane >> 4;
    const int t0   = blockIdx.x * 128;
    const int nr   = blockIdx.y;
    const int n    = n0 + nr;
    const int cb   = blockIdx.z;

    __shared__ unsigned short smem[32768];   // 65536 B: 2 bufs x (2 planes x (A 4096 + B 4096))

    // staging lane slots (R6-verified swizzle q' = q ^ ((row>>1)&3))
    const int rl0 = tid >> 2;
    const int rl1 = 64 + (tid >> 2);
    const int q0  = (tid & 3) ^ ((rl0 >> 1) & 3);
    const int q1  = (tid & 3) ^ ((rl1 >> 1) & 3);

    const unsigned short* xn = xb + (size_t)nr * 1024 * 512;
    int aoff0[3], aoff1[3];
#pragma unroll
    for (int kk = 0; kk < 3; ++kk) {
        aoff0[kk] = reflect_idx(t0 + rl0 + 8 * kk - 8, 1024) * 512 + q0 * 8;
        aoff1[kk] = reflect_idx(t0 + rl1 + 8 * kk - 8, 1024) * 512 + q1 * 8;
    }
    const unsigned short* wp0 = wb + (size_t)(cb * 128 + rl0) * 512 + q0 * 8;
    const unsigned short* wp1 = wb + (size_t)(cb * 128 + rl1) * 512 + q1 * 8;

    const int atom = qd ^ ((tq >> 1) & 3);

    f32x4 acc[4][4];
#pragma unroll
    for (int a = 0; a < 4; ++a)
#pragma unroll
        for (int b = 0; b < 4; ++b) acc[a][b] = (f32x4){0.f, 0.f, 0.f, 0.f};

    // prologue: stage interval 0 (kk=0, ci 0..63) into buf 0
#pragma unroll
    for (int p = 0; p < 2; ++p) {
        GLDS16(xn + aoff0[0] + p * 32, &smem[p * 8192 + tid * 8]);
        GLDS16(xn + aoff1[0] + p * 32, &smem[p * 8192 + 2048 + tid * 8]);
        GLDS16(wp0 + p * 32, &smem[p * 8192 + 4096 + tid * 8]);
        GLDS16(wp1 + p * 32, &smem[p * 8192 + 6144 + tid * 8]);
    }

#pragma unroll
    for (int c = 0; c < 24; ++c) {
        const int bo = (c & 1) * 16384;
        __syncthreads();   // buf ready (vmcnt0 drain happens here)
        if (c < 23) {
            const int nc = c + 1, nk = nc >> 3, nj = nc & 7;
            const int no = ((c + 1) & 1) * 16384;
#pragma unroll
            for (int p = 0; p < 2; ++p) {
                const int col = nj * 64 + p * 32;
                GLDS16(xn + aoff0[nk] + col, &smem[no + p * 8192 + tid * 8]);
                GLDS16(xn + aoff1[nk] + col, &smem[no + p * 8192 + 2048 + tid * 8]);
                GLDS16(wp0 + (size_t)nk * 131072 + col, &smem[no + p * 8192 + 4096 + tid * 8]);
                GLDS16(wp1 + (size_t)nk * 131072 + col, &smem[no + p * 8192 + 6144 + tid * 8]);
            }
        }
#pragma unroll
        for (int p = 0; p < 2; ++p) {
            const int ab = bo + p * 8192;
            bf16x8_t Af[4], Bf[4];
#pragma unroll
            for (int ts = 0; ts < 4; ++ts)
                Af[ts] = *(const bf16x8_t*)&smem[ab + (tw * 64 + ts * 16 + tq) * 32 + atom * 8];
#pragma unroll
            for (int cs = 0; cs < 4; ++cs)
                Bf[cs] = *(const bf16x8_t*)&smem[ab + 4096 + (cw * 64 + cs * 16 + tq) * 32 + atom * 8];
#pragma unroll
            for (int ts = 0; ts < 4; ++ts)
#pragma unroll
                for (int cs = 0; cs < 4; ++cs)
                    acc[ts][cs] = __builtin_amdgcn_mfma_f32_16x16x32_bf16(
                        Af[ts], Bf[cs], acc[ts][cs], 0, 0, 0);
        }
    }

    // epilogue: bn + relu -> bf16 -> LDS transpose [128t][128co] (stride 136)
    __syncthreads();
#pragma unroll
    for (int cs = 0; cs < 4; ++cs) {
        int col = cw * 64 + cs * 16 + tq;
        int co  = cb * 128 + col;
        float iv = g[co] / sqrtf(vr[co] + 1e-5f);
        float sh = be[co] - mn[co] * iv;
#pragma unroll
        for (int ts = 0; ts < 4; ++ts)
#pragma unroll
            for (int rg = 0; rg < 4; ++rg)
                smem[(tw * 64 + ts * 16 + qd * 4 + rg) * 136 + col] =
                    f2bf(fmaxf(fmaf(acc[ts][cs][rg], iv, sh), 0.0f));
    }
    __syncthreads();
    const int srow = tid >> 4, sseg = tid & 15;
#pragma unroll
    for (int p = 0; p < 8; ++p) {
        int row = p * 16 + srow;
        unsigned short* yp = y1t + ((size_t)n * 1024 + t0 + row) * 256 + cb * 128 + sseg * 8;
        *(uint4*)yp = *(const uint4*)&smem[row * 136 + sseg * 8];
    }
}

// ---------------------------------------------------------------------------
// K2 v2: upsample2(y1t) -> conv2 via bf16 MFMA, ping-pong staging (1 barrier
// per chunk; staging of chunk c+1 overlaps MFMA of chunk c across waves).
// Output TRANSPOSED fp32: y2t[n][2048t][32co].
__global__ __launch_bounds__(256, 2) void k2_mfma(
    const unsigned short* __restrict__ y1t, const unsigned short* __restrict__ w2b,
    const float* __restrict__ g, const float* __restrict__ be,
    const float* __restrict__ mn, const float* __restrict__ vr,
    float* __restrict__ y2t)
{
    const int tid  = threadIdx.x;
    const int lane = tid & 63;
    const int w    = tid >> 6;
    const int tq   = lane & 15;
    const int qd   = lane >> 4;
    const int t0   = blockIdx.x * 256;
    const int n    = blockIdx.y;

    __shared__ union SM {
        unsigned short us[2][288 * 40];   // 46080 B
        float tr[256 * 36];               // 36864 B (aliases, used after final sync)
    } sm;

    f32x4 acc[4][2];
#pragma unroll
    for (int a = 0; a < 4; ++a)
#pragma unroll
        for (int b = 0; b < 2; ++b) acc[a][b] = (f32x4){0.f, 0.f, 0.f, 0.f};

    const unsigned short* yn = y1t + (size_t)n * 1024 * 256;

    // stage chunk ch (32 ci starting at ch*32) into buffer buf
    auto stage = [&](int ch, int buf) {
        const int ci0 = ch * 32;
        for (int idx = tid; idx < 1152; idx += 256) {
            int r = idx >> 2, gq = idx & 3;
            int u = reflect_idx(t0 - 16 + r, 2048);
            float src = fmaxf((float)u * 0.5f - 0.25f, 0.0f);
            int i0 = (int)src;
            float wl = src - (float)i0;
            int i1 = i0 + 1 > 1023 ? 1023 : i0 + 1;
            const unsigned short* p0 = yn + (size_t)i0 * 256 + ci0 + gq * 8;
            const unsigned short* p1 = yn + (size_t)i1 * 256 + ci0 + gq * 8;
            uint4 ua = *(const uint4*)p0;
            uint4 ub = *(const uint4*)p1;
            const unsigned short* sa = (const unsigned short*)&ua;
            const unsigned short* sb = (const unsigned short*)&ub;
            unsigned short pk[8];
#pragma unroll
            for (int j = 0; j < 8; ++j) {
                float a = bf2f(sa[j]);
                float b = bf2f(sb[j]);
                pk[j] = f2bf(a + wl * (b - a));
            }
            *(uint4*)&sm.us[buf][r * 40 + gq * 8] = *(const uint4*)pk;
        }
    };

    stage(0, 0);
    for (int ch = 0; ch < 8; ++ch) {
        const int buf = ch & 1;
        __syncthreads();   // buf staged; prev chunk's readers of buf^1 done
        if (ch < 7) stage(ch + 1, buf ^ 1);

        const int ci0 = ch * 32;
        bf16x8_t Bf[2][3];
#pragma unroll
        for (int cs = 0; cs < 2; ++cs)
#pragma unroll
            for (int kk = 0; kk < 3; ++kk)
                Bf[cs][kk] = *(const bf16x8_t*)(w2b +
                    ((size_t)(kk * 32 + cs * 16 + tq)) * 256 + ci0 + qd * 8);

        bf16x8_t Af[6];
#pragma unroll
        for (int s = 0; s < 6; ++s)
            Af[s] = *(const bf16x8_t*)&sm.us[buf][(w * 64 + s * 16 + tq) * 40 + qd * 8];

#pragma unroll
        for (int ts = 0; ts < 4; ++ts)
#pragma unroll
            for (int cs = 0; cs < 2; ++cs)
#pragma unroll
                for (int kk = 0; kk < 3; ++kk)
                    acc[ts][cs] = __builtin_amdgcn_mfma_f32_16x16x32_bf16(
                        Af[ts + kk], Bf[cs][kk], acc[ts][cs], 0, 0, 0);
    }

    __syncthreads();
#pragma unroll
    for (int cs = 0; cs < 2; ++cs) {
        int co = cs * 16 + tq;
        float iv = g[co] / sqrtf(vr[co] + 1e-5f);
        float sh = be[co] - mn[co] * iv;
#pragma unroll
        for (int ts = 0; ts < 4; ++ts)
#pragma unroll
            for (int rg = 0; rg < 4; ++rg) {
                int tl = w * 64 + ts * 16 + qd * 4 + rg;
                sm.tr[tl * 36 + co] = fmaxf(fmaf(acc[ts][cs][rg], iv, sh), 0.0f);
            }
    }
    __syncthreads();
    float* yo = y2t + ((size_t)n * 2048 + t0 + tid) * 32;
#pragma unroll
    for (int j = 0; j < 8; ++j)
        *(float4*)(yo + j * 4) = *(const float4*)&sm.tr[tid * 36 + j * 4];
}

// ---------------------------------------------------------------------------
// K3: upsample2(y2t) -> conv3 (32->3, d=32) + bias, transposed store (unchanged)
__global__ __launch_bounds__(256, 2) void k3_out(
    const float* __restrict__ y2t, const float* __restrict__ w3,
    const float* __restrict__ bias, float* __restrict__ out)
{
    const int tid = threadIdx.x;
    const int t0 = blockIdx.x * 256;
    const int n  = blockIdx.y;

    __shared__ float us[32 * 321];
    __shared__ float wsh[288];

    for (int idx = tid; idx < 288; idx += 256) wsh[idx] = w3[idx];

    const float* yn = y2t + (size_t)n * 2048 * 32;
    for (int idx = tid; idx < 1280; idx += 256) {
        int r = idx >> 2, gq = idx & 3;
        int u = reflect_idx(t0 - 32 + r, 4096);
        float src = fmaxf((float)u * 0.5f - 0.25f, 0.0f);
        int i0 = (int)src;
        float wl = src - (float)i0;
        int i1 = i0 + 1 > 2047 ? 2047 : i0 + 1;
        const float* p0 = yn + (size_t)i0 * 32 + gq * 8;
        const float* p1 = yn + (size_t)i1 * 32 + gq * 8;
        float4 a0 = *(const float4*)p0;
        float4 a1 = *(const float4*)(p0 + 4);
        float4 b0 = *(const float4*)p1;
        float4 b1 = *(const float4*)(p1 + 4);
        float v[8];
        v[0] = a0.x + wl * (b0.x - a0.x); v[1] = a0.y + wl * (b0.y - a0.y);
        v[2] = a0.z + wl * (b0.z - a0.z); v[3] = a0.w + wl * (b0.w - a0.w);
        v[4] = a1.x + wl * (b1.x - a1.x); v[5] = a1.y + wl * (b1.y - a1.y);
        v[6] = a1.z + wl * (b1.z - a1.z); v[7] = a1.w + wl * (b1.w - a1.w);
#pragma unroll
        for (int j = 0; j < 8; ++j)
            us[(gq * 8 + j) * 321 + r] = v[j];
    }
    __syncthreads();

    float a0 = 0.0f, a1 = 0.0f, a2 = 0.0f;
#pragma unroll 8
    for (int ci = 0; ci < 32; ++ci) {
        float x0 = us[ci * 321 + tid];
        float x1 = us[ci * 321 + tid + 32];
        float x2 = us[ci * 321 + tid + 64];
        a0 = fmaf(wsh[(0 * 32 + ci) * 3 + 0], x0, a0);
        a0 = fmaf(wsh[(0 * 32 + ci) * 3 + 1], x1, a0);
        a0 = fmaf(wsh[(0 * 32 + ci) * 3 + 2], x2, a0);
        a1 = fmaf(wsh[(1 * 32 + ci) * 3 + 0], x0, a1);
        a1 = fmaf(wsh[(1 * 32 + ci) * 3 + 1], x1, a1);
        a1 = fmaf(wsh[(1 * 32 + ci) * 3 + 2], x2, a1);
        a2 = fmaf(wsh[(2 * 32 + ci) * 3 + 0], x0, a2);
        a2 = fmaf(wsh[(2 * 32 + ci) * 3 + 1], x1, a2);
        a2 = fmaf(wsh[(2 * 32 + ci) * 3 + 2], x2, a2);
    }
    int b = n >> 2, s = n & 3;
    int t = t0 + tid;
    size_t ob = ((size_t)(b * 3) * 4096 + t) * 4 + s;
    out[ob]         = a0 + bias[0];
    out[ob + 16384] = a1 + bias[1];
    out[ob + 32768] = a2 + bias[2];
}

// ---------------------------------------------------------------------------
// K4b: CE partial sums (one atomic per block) + per-(b,s) valid flags
// (fused former k4a). Block covers one b (blk>>6), all 4 s.
__global__ __launch_bounds__(256) void k4b_ce(
    const float* __restrict__ x, const float* __restrict__ tg, float* lacc)
{
    int i = blockIdx.x * 256 + threadIdx.x;
    int s = i & 3;
    int t = (i >> 2) & 4095;
    int b = i >> 14;
    size_t base = ((size_t)(b * 3) * 4096 + t) * 4 + s;
    float x0 = x[base], x1 = x[base + 16384], x2 = x[base + 32768];
    float mx = fmaxf(x0, fmaxf(x1, x2));
    float e0 = expf(x0 - mx), e1 = expf(x1 - mx), e2 = expf(x2 - mx);
    float lse = mx + logf(e0 + e1 + e2);
    float g0 = tg[base], g1 = tg[base + 16384], g2 = tg[base + 32768];
    float v = g0 * (lse - x0) + g1 * (lse - x1) + g2 * (lse - x2);
    bool nz = (g0 != 0.0f) | (g1 != 0.0f) | (g2 != 0.0f);

    __shared__ float wsum[4];
    __shared__ int sf[4];
    if (threadIdx.x < 4) sf[threadIdx.x] = 0;
    __syncthreads();
    if (nz) sf[s] = 1;

    for (int off = 32; off > 0; off >>= 1) v += __shfl_down(v, off);
    int lane = threadIdx.x & 63, wid = threadIdx.x >> 6;
    if (lane == 0) wsum[wid] = v;
    __syncthreads();
    if (threadIdx.x == 0)
        atomicAdd(lacc, wsum[0] + wsum[1] + wsum[2] + wsum[3]);
    if (threadIdx.x < 4 && sf[threadIdx.x])
        atomicOr((int*)lacc + 8 + b * 4 + threadIdx.x, 1);
}

// K4c: loss = sum / (num_valid * T)
__global__ void k4c_final(const float* lacc, float* out) {
    if (threadIdx.x == 0) {
        float sum = lacc[0];
        const int* vf = (const int*)lacc + 8;
        int num = 0;
#pragma unroll
        for (int j = 0; j < 64; ++j) num += (vf[j] != 0);
        out[786432] = sum / ((float)num * 4096.0f);
    }
}

// ---------------------------------------------------------------------------
extern "C" void kernel_launch(void* const* d_in, const int* in_sizes, int n_in,
                              void* d_out, int out_size, void* d_ws, size_t ws_size,
                              hipStream_t stream) {
    (void)in_sizes; (void)n_in; (void)out_size;
    const float* fusion  = (const float*)d_in[0];
    const float* targets = (const float*)d_in[1];
    const float* w1  = (const float*)d_in[2];
    const float* g1  = (const float*)d_in[3];
    const float* be1 = (const float*)d_in[4];
    const float* mn1 = (const float*)d_in[5];
    const float* vr1 = (const float*)d_in[6];
    const float* w2  = (const float*)d_in[7];
    const float* g2  = (const float*)d_in[8];
    const float* be2 = (const float*)d_in[9];
    const float* mn2 = (const float*)d_in[10];
    const float* vr2 = (const float*)d_in[11];
    const float* w3  = (const float*)d_in[12];
    const float* b3  = (const float*)d_in[13];
    float* out = (float*)d_out;

    char* ws = (char*)d_ws;
    unsigned short* y1t = (unsigned short*)ws;              // 33,554,432 B
    unsigned short* xb  = (unsigned short*)(ws + 33554432); // 16 or 64 MB
    float* y2t = (float*)(ws + 33554432);                   // 16 MB, aliases xb

    const bool single = ws_size >= 101500000ull;
    size_t woff = single ? (33554432ull + 67108864ull) : (33554432ull + 16777216ull);
    unsigned short* wb  = (unsigned short*)(ws + woff);            // 786,432 B
    unsigned short* w2b = (unsigned short*)(ws + woff + 786432);   //  49,152 B
    float* lacc = (float*)(ws + woff + 786432 + 49152);            //     512 B

    kprep<<<1632, 256, 0, stream>>>(w1, w2, wb, w2b, lacc);
    if (single) {
        kx_t<<<dim3(16, 8, 64), 256, 0, stream>>>(fusion, xb, 0);
        k1_mfma<<<dim3(8, 64, 2), 256, 0, stream>>>(xb, wb, g1, be1, mn1, vr1, y1t, 0);
    } else {
        for (int r = 0; r < 4; ++r) {
            kx_t<<<dim3(16, 8, 16), 256, 0, stream>>>(fusion, xb, r * 16);
            k1_mfma<<<dim3(8, 16, 2), 256, 0, stream>>>(xb, wb, g1, be1, mn1, vr1, y1t, r * 16);
        }
    }
    k2_mfma<<<dim3(8, 64), 256, 0, stream>>>(y1t, w2b, g2, be2, mn2, vr2, y2t);
    k3_out<<<dim3(16, 64), 256, 0, stream>>>(y2t, w3, b3, out);
    k4b_ce<<<1024, 256, 0, stream>>>(out, targets, lacc);
    k4c_final<<<1, 64, 0, stream>>>(lacc, out);
}